// Round 9
// baseline (181.703 us; speedup 1.0000x reference)
//
#include <hip/hip_runtime.h>
#include <math.h>

#define AB 128   // A == B == 128
#define NN 64    // N
#define HD 1024  // H

// fp32 -> f16 hi/lo split scales. Z ~ N(0,1) -> x256 keeps lo normal;
// F entries ~1e-2 -> x64. out = acc * gamma * 2^-20.
#define SFZ 256.0f
#define SFF 64.0f
#define DESCALE (1.0f / 1048576.0f)  // 2^-(8+6+6)

typedef _Float16 half8 __attribute__((ext_vector_type(8)));
typedef float f32x4 __attribute__((ext_vector_type(4)));
typedef unsigned u32x4 __attribute__((ext_vector_type(4)));

#define MFMA16 __builtin_amdgcn_mfma_f32_16x16x32_f16

// ---------------------------------------------------------------------------
// ws layout (halfs), both filterbanks in K-major granule form:
//   kaddr(row, k) = (k>>3)*512 + row*8 + (k&7)      (k = image axis, row = n/m)
//   [0,     8192)   FXhi ; [8192, 16384)  FXlo
//   [16384, 24576)  FYhi ; [24576, 32768)  FYlo
//   float at float-index 16384 (byte 65536): gamma * 2^-20
// ---------------------------------------------------------------------------

__device__ __forceinline__ float wave_reduce(float v) {
  v += __shfl_down(v, 32);
  v += __shfl_down(v, 16);
  v += __shfl_down(v, 8);
  v += __shfl_down(v, 4);
  v += __shfl_down(v, 2);
  v += __shfl_down(v, 1);
  return v;  // valid in lane 0
}

__global__ __launch_bounds__(1024) void fb_setup(
    const float* __restrict__ h, const float* __restrict__ Ww,
    const float* __restrict__ Wb, void* __restrict__ wsv) {
  __shared__ float redp[16][5];
  __shared__ float reds[16][2];
  __shared__ float sc[5];
  __shared__ float ssum[2];
  const int tid = threadIdx.x;
  const int lane = tid & 63;
  const int wv = tid >> 6;

  const float hv = h[tid];
  float p[5];
#pragma unroll
  for (int j = 0; j < 5; ++j) p[j] = hv * Ww[j * HD + tid];
#pragma unroll
  for (int j = 0; j < 5; ++j) {
    float r = wave_reduce(p[j]);
    if (lane == 0) redp[wv][j] = r;
  }
  __syncthreads();
  if (tid < 5) {
    float s = Wb[tid];
#pragma unroll
    for (int w = 0; w < 16; ++w) s += redp[w][tid];
    sc[tid] = s;
  }
  __syncthreads();

  const float gt_X = sc[0], gt_Y = sc[1], log_var = sc[2], log_dt = sc[3];
  const float var = expf(log_var + 1e-8f);
  const float g_X = (129.0f * (gt_X + 1.0f)) / 2.0f;
  const float g_Y = (129.0f * (gt_Y + 1.0f)) / 2.0f;
  const float d = (expf(log_dt) * 127.0f) / 63.0f;
  const float twovar = 2.0f * var;

  float fyv[8], fxv[8];
  float sY = 0.f, sX = 0.f;
#pragma unroll
  for (int c = 0; c < 8; ++c) {
    const int idx = tid + 1024 * c;
    const int n = idx >> 7;
    const int col = idx & 127;
    const float idxn = (float)n - 32.5f;
    const float muX = g_X + idxn * d;
    const float muY = g_Y + idxn * d;
    const float dx = (float)col - muX;
    const float dy = (float)col - muY;
    const float fx = expf(-(dx * dx) / twovar);
    const float fy = expf(-(dy * dy) / twovar);
    fyv[c] = fy;
    fxv[c] = fx;
    sY += fy;
    sX += fx;
  }
  {
    float rY = wave_reduce(sY);
    float rX = wave_reduce(sX);
    if (lane == 0) { reds[wv][0] = rY; reds[wv][1] = rX; }
  }
  __syncthreads();
  if (tid < 2) {
    float s = 0.f;
#pragma unroll
    for (int w = 0; w < 16; ++w) s += reds[w][tid];
    ssum[tid] = s;
  }
  __syncthreads();
  const float invY = 1.0f / ssum[0];
  const float invX = 1.0f / ssum[1];

  _Float16* FXk = (_Float16*)wsv;                 // hi, lo at +8192
  _Float16* FYk = (_Float16*)wsv + 2 * NN * AB;   // hi, lo at +8192

#pragma unroll
  for (int c = 0; c < 8; ++c) {
    const int idx = tid + 1024 * c;  // n*128 + col
    const int n = idx >> 7;
    const int col = idx & 127;
    const float vy = fyv[c] * invY * SFF;
    const float vx = fxv[c] * invX * SFF;
    const _Float16 yh = (_Float16)vy;
    const _Float16 xh2 = (_Float16)vx;
    const int kaddr = ((col >> 3) << 9) + (n << 3) + (col & 7);
    FXk[kaddr] = xh2;
    FXk[8192 + kaddr] = (_Float16)(vx - (float)xh2);
    FYk[kaddr] = yh;
    FYk[8192 + kaddr] = (_Float16)(vy - (float)yh);
  }
  if (tid == 0) ((float*)wsv)[16384] = expf(sc[4]) * DESCALE;
}

// ---------------------------------------------------------------------------
// fb_filt: 512 blocks x 256 thr (4 waves); wave w of block b owns image-half
// slot = 4b+w (img = slot>>1, which = slot&1). ALL 2048 waves co-resident
// (2 blocks/CU x 64 KB LDS, VGPR<=256 -> 2 waves/SIMD). ONE barrier total
// (after shared FX copy); each wave then runs a private 4-chunk pipeline:
//   chunk ac (a in [32ac,32ac+32)):
//     stage1: T[64x32] = FXs @ Zs[chunk]^T  (96 MFMAs, FX frags from LDS)
//     T -> wave-private 8 KB LDS slice (b16 hi/lo planes, no barrier)
//     issue Z(ac+1) [16 asm loads]  -> fly under stage2
//     stage2: out += FYs[:,chunk] @ T^T     (48 MFMAs)
//     issue FY(ac+1) [8 asm loads]  -> fly under next stage1
// Counted vmcnt: ks waits 20/16/12/8, stage2 wait 16 (last chunk 0).
// 3-product f16 emulation: Ahi*Bhi + Ahi*Blo + Alo*Bhi (fp32 acc).
// ---------------------------------------------------------------------------
__device__ __forceinline__ void split8(const f32x4 z0, const f32x4 z1,
                                       float s, half8& hi, half8& lo) {
#pragma unroll
  for (int e = 0; e < 8; ++e) {
    const float q = (e < 4 ? z0[e] : z1[e - 4]) * s;
    const _Float16 hh = (_Float16)q;
    hi[e] = hh;
    lo[e] = (_Float16)(q - (float)hh);
  }
}

#define ZLD(dst, base, OFF)                                              \
  asm volatile("global_load_dwordx4 %0, %1, off offset:" #OFF            \
               : "=v"(dst) : "v"(base))

#define WAITVM_SB(N)                                                     \
  do {                                                                   \
    asm volatile("s_waitcnt vmcnt(" #N ")");                             \
    __builtin_amdgcn_sched_barrier(0);                                   \
  } while (0)

__global__ __launch_bounds__(256, 2) void fb_filt(
    const float* __restrict__ x, const float* __restrict__ xh,
    const void* __restrict__ wsv, float* __restrict__ out) {
  // [0,16384): shared FX hi/lo planes. [16384+wv*4096, +4096): wave-private T.
  __shared__ __align__(16) _Float16 S_lds[32768];  // 64 KB

  const int tid = threadIdx.x;
  const int lane = tid & 63;
  const int wv = tid >> 6;            // 0..3
  const int l15 = lane & 15;
  const int h4 = lane >> 4;           // 0..3
  const int slot = (blockIdx.x << 2) | wv;
  const int img = slot >> 1;
  const int which = slot & 1;
  const float* __restrict__ Z = (which ? xh : x) + (size_t)img * (AB * AB);
  const _Float16* __restrict__ FYk = (const _Float16*)wsv + 2 * NN * AB;
  const float gamma_eff = ((const float*)wsv)[16384];
  const int Tb = 16384 + (wv << 12);  // halfs; hi [0,2048), lo [2048,4096)

  // ---- shared FX copy (32 KB), the ONLY barrier ----
  {
    const u32x4* __restrict__ src = (const u32x4*)wsv;  // 2048 granules
    u32x4* __restrict__ dst = (u32x4*)S_lds;
#pragma unroll
    for (int c = 0; c < 8; ++c) dst[c * 256 + tid] = src[c * 256 + tid];
  }
  __syncthreads();  // drains copy loads (vmcnt -> 0)

  f32x4 z0_0, z0_1, z0_2, z0_3, z1_0, z1_1, z1_2, z1_3;
  f32x4 z2_0, z2_1, z2_2, z2_3, z3_0, z3_1, z3_2, z3_3;
  half8 fyh[4], fyl[4];
  f32x4 acc[4][2];    // stage-1 T accumulator, re-zeroed per chunk
  f32x4 acc2[4][4];   // output accumulator [nt][mt]
#pragma unroll
  for (int nt = 0; nt < 4; ++nt)
#pragma unroll
    for (int mt = 0; mt < 4; ++mt) acc2[nt][mt] = {0.f, 0.f, 0.f, 0.f};

#define ISSUE_Z(AC)                                                      \
  do {                                                                   \
    const float* zc0_ = Z + (32 * (AC) + l15) * AB + 8 * h4;             \
    const float* zc1_ = zc0_ + 16 * AB;                                  \
    ZLD(z0_0, zc0_, 0);   ZLD(z0_1, zc0_, 16);                           \
    ZLD(z0_2, zc1_, 0);   ZLD(z0_3, zc1_, 16);                           \
    ZLD(z1_0, zc0_, 128); ZLD(z1_1, zc0_, 144);                          \
    ZLD(z1_2, zc1_, 128); ZLD(z1_3, zc1_, 144);                          \
    ZLD(z2_0, zc0_, 256); ZLD(z2_1, zc0_, 272);                          \
    ZLD(z2_2, zc1_, 256); ZLD(z2_3, zc1_, 272);                          \
    ZLD(z3_0, zc0_, 384); ZLD(z3_1, zc0_, 400);                          \
    ZLD(z3_2, zc1_, 384); ZLD(z3_3, zc1_, 400);                          \
  } while (0)

#define ISSUE_FY(AC)                                                     \
  do {                                                                   \
    const _Float16* fh_ = FYk + ((4 * (AC) + h4) << 9) + (l15 << 3);     \
    const _Float16* fl_ = fh_ + 8192;                                    \
    ZLD(fyh[0], fh_, 0);   ZLD(fyh[1], fh_, 256);                        \
    ZLD(fyh[2], fh_, 512); ZLD(fyh[3], fh_, 768);                        \
    ZLD(fyl[0], fl_, 0);   ZLD(fyl[1], fl_, 256);                        \
    ZLD(fyl[2], fl_, 512); ZLD(fyl[3], fl_, 768);                        \
  } while (0)

#define S1(KS, WN)                                                       \
  do {                                                                   \
    WAITVM_SB(WN);                                                       \
    half8 bh0_, bl0_, bh1_, bl1_;                                        \
    split8(z##KS##_0, z##KS##_1, SFZ, bh0_, bl0_);                       \
    split8(z##KS##_2, z##KS##_3, SFZ, bh1_, bl1_);                       \
    const int gb_ = ((4 * (KS) + h4) << 9);                              \
    _Pragma("unroll")                                                    \
    for (int mt = 0; mt < 4; ++mt) {                                     \
      const _Float16* ap_ = S_lds + gb_ + ((16 * mt + l15) << 3);        \
      const half8 ah_ = *(const half8*)ap_;                              \
      const half8 al_ = *(const half8*)(ap_ + 8192);                     \
      acc[mt][0] = MFMA16(ah_, bh0_, acc[mt][0], 0, 0, 0);               \
      acc[mt][0] = MFMA16(ah_, bl0_, acc[mt][0], 0, 0, 0);               \
      acc[mt][0] = MFMA16(al_, bh0_, acc[mt][0], 0, 0, 0);               \
      acc[mt][1] = MFMA16(ah_, bh1_, acc[mt][1], 0, 0, 0);               \
      acc[mt][1] = MFMA16(ah_, bl1_, acc[mt][1], 0, 0, 0);               \
      acc[mt][1] = MFMA16(al_, bh1_, acc[mt][1], 0, 0, 0);               \
    }                                                                    \
  } while (0)

#define TSTORE                                                           \
  do {                                                                   \
    _Pragma("unroll")                                                    \
    for (int mt = 0; mt < 4; ++mt) {                                     \
      _Pragma("unroll")                                                  \
      for (int j = 0; j < 2; ++j) {                                      \
        const int ab_ = Tb + ((2 * j + (l15 >> 3)) << 9) + (l15 & 7);    \
        _Pragma("unroll")                                                \
        for (int r = 0; r < 4; ++r) {                                    \
          const int row_ = 16 * mt + 4 * h4 + r;                         \
          const float v_ = acc[mt][j][r];                                \
          const _Float16 hh_ = (_Float16)v_;                             \
          const _Float16 ll_ = (_Float16)(v_ - (float)hh_);              \
          S_lds[ab_ + (row_ << 3)] = hh_;                                \
          S_lds[ab_ + 2048 + (row_ << 3)] = ll_;                         \
        }                                                                \
      }                                                                  \
    }                                                                    \
  } while (0)

#define STAGE2                                                           \
  do {                                                                   \
    _Pragma("unroll")                                                    \
    for (int mt = 0; mt < 4; ++mt) {                                     \
      const _Float16* bp_ = S_lds + Tb + (h4 << 9) + ((16 * mt + l15) << 3); \
      const half8 bh_ = *(const half8*)bp_;                              \
      const half8 bl_ = *(const half8*)(bp_ + 2048);                     \
      _Pragma("unroll")                                                  \
      for (int nt = 0; nt < 4; ++nt) {                                   \
        acc2[nt][mt] = MFMA16(fyh[nt], bh_, acc2[nt][mt], 0, 0, 0);      \
        acc2[nt][mt] = MFMA16(fyh[nt], bl_, acc2[nt][mt], 0, 0, 0);      \
        acc2[nt][mt] = MFMA16(fyl[nt], bh_, acc2[nt][mt], 0, 0, 0);      \
      }                                                                  \
    }                                                                    \
  } while (0)

#define ZERO_ACC                                                         \
  do {                                                                   \
    _Pragma("unroll")                                                    \
    for (int mt = 0; mt < 4; ++mt) {                                     \
      acc[mt][0] = {0.f, 0.f, 0.f, 0.f};                                 \
      acc[mt][1] = {0.f, 0.f, 0.f, 0.f};                                 \
    }                                                                    \
  } while (0)

  // ---- prologue: fill the pipe (Z first, then FY -> 24 outstanding) ----
  ISSUE_Z(0);
  ISSUE_FY(0);

  // ---- chunk 0 ----
  ZERO_ACC;
  S1(0, 20); S1(1, 16); S1(2, 12); S1(3, 8);
  TSTORE;
  ISSUE_Z(1);
  WAITVM_SB(16);   // FY(0) ready; Z(1) still flying under stage2
  STAGE2;
  ISSUE_FY(1);

  // ---- chunk 1 ----
  ZERO_ACC;
  S1(0, 20); S1(1, 16); S1(2, 12); S1(3, 8);
  TSTORE;
  ISSUE_Z(2);
  WAITVM_SB(16);
  STAGE2;
  ISSUE_FY(2);

  // ---- chunk 2 ----
  ZERO_ACC;
  S1(0, 20); S1(1, 16); S1(2, 12); S1(3, 8);
  TSTORE;
  ISSUE_Z(3);
  WAITVM_SB(16);
  STAGE2;
  ISSUE_FY(3);

  // ---- chunk 3 (last: no new issues, drain) ----
  ZERO_ACC;
  S1(0, 20); S1(1, 16); S1(2, 12); S1(3, 8);
  TSTORE;
  WAITVM_SB(0);
  STAGE2;

  // ---- Epilogue: out[16nt+4h4+r][16mt+l15] ----
  float* __restrict__ ob = out + (size_t)img * 8192 + which * 4096;
#pragma unroll
  for (int nt = 0; nt < 4; ++nt) {
#pragma unroll
    for (int mt = 0; mt < 4; ++mt) {
#pragma unroll
      for (int r = 0; r < 4; ++r) {
        ob[(16 * nt + 4 * h4 + r) * 64 + 16 * mt + l15] =
            acc2[nt][mt][r] * gamma_eff;
      }
    }
  }
}

extern "C" void kernel_launch(void* const* d_in, const int* in_sizes, int n_in,
                              void* d_out, int out_size, void* d_ws, size_t ws_size,
                              hipStream_t stream) {
  const float* x = (const float*)d_in[0];
  const float* xh = (const float*)d_in[1];
  const float* h = (const float*)d_in[2];
  const float* Ww = (const float*)d_in[3];
  const float* Wb = (const float*)d_in[4];
  float* outp = (float*)d_out;

  fb_setup<<<1, 1024, 0, stream>>>(h, Ww, Wb, d_ws);
  fb_filt<<<512, 256, 0, stream>>>(x, xh, (const void*)d_ws, outp);
}